// Round 1
// baseline (522.112 us; speedup 1.0000x reference)
//
#include <hip/hip_runtime.h>
#include <stdint.h>

#define HID    1024
#define TYPES  1001
#define NGATES 5120              // 5 gates * 1024
#define BATCH  32
#define SEQLEN 512
#define TB     (BATCH * SEQLEN)  // 16384
#define TBH    ((size_t)TB * HID)          // floats per output plane

#define BK 64                    // K-step (bf16 -> 128B LDS rows)
#define TM 128                   // M tile (types)
#define TN 160                   // N tile (gate*hidden) -> 8 x 32 = 256 blocks, 1/CU

typedef __attribute__((ext_vector_type(4))) float  f32x4;
typedef __attribute__((ext_vector_type(8))) __bf16 bf16x8;

// round-to-nearest-even f32 -> bf16 bits
__device__ __forceinline__ uint32_t f2bf(float f) {
    uint32_t u = __float_as_uint(f);
    return (u + 0x7FFFu + ((u >> 16) & 1u)) >> 16;
}

// gate g in {0:gi,1:gz,2:go,3:gib,4:gd} -> source row offset in W_rec / b_rec
// offsets: gi=0, gz=2048, go=3072, gib=4096, gd=6144
__device__ __forceinline__ int gate_off(int g) {
    return (g + (g >= 1) + (g >= 4)) << 10;
}

// async global->LDS, 16B per lane (LDS dest must be uniform-base + lane*16)
#define GLD16(gp, lp) __builtin_amdgcn_global_load_lds(                        \
    (const __attribute__((address_space(1))) void*)(uintptr_t)(gp),            \
    (__attribute__((address_space(3))) void*)(uint32_t)(uintptr_t)(lp),        \
    16, 0, 0)

// ---------------------------------------------------------------------------
// Kernel 1: convert emb (1001x1024) and gathered W rows (5120x1024) to bf16.
// ---------------------------------------------------------------------------
__global__ __launch_bounds__(256) void convert_kernel(
    const float* __restrict__ emb, const float* __restrict__ Wrec,
    uint16_t* __restrict__ Ebf, uint16_t* __restrict__ Wbf)
{
    const int row = blockIdx.x;
    const int tid = threadIdx.x;
    const float* src;
    uint16_t* dst;
    if (row < TYPES) {
        src = emb + (size_t)row * HID;
        dst = Ebf + (size_t)row * HID;
    } else {
        const int n = row - TYPES;           // 0..5119
        const int g = n >> 10;
        const int h = n & 1023;
        src = Wrec + (size_t)(gate_off(g) + h) * (2 * HID);  // W_rec row stride = 2H
        dst = Wbf + (size_t)n * HID;
    }
    float4 v = ((const float4*)src)[tid];
    uint2 p;
    p.x = f2bf(v.x) | (f2bf(v.y) << 16);
    p.y = f2bf(v.z) | (f2bf(v.w) << 16);
    ((uint2*)dst)[tid] = p;
}

// ---------------------------------------------------------------------------
// Kernel 2: bf16 MFMA GEMM, 128x160 tile, BK=64, double-buffered LDS with
// prefetch-before-compute (2-phase). grid = (8,32) = 256 blocks = 1/CU.
// LDS rows are 128B -> XOR-swizzle 16B chunks (chunk ^= row&7); since
// global_load_lds writes linearly, the *global source* chunk is pre-swizzled
// and the ds_read applies the same XOR (both-sides rule).
// Output table G interleaved: G[type][gate][h], fp32, activated.
// ---------------------------------------------------------------------------
__global__ __launch_bounds__(256) void gemm_gates(
    const uint16_t* __restrict__ E, const uint16_t* __restrict__ W,
    const float* __restrict__ brec, float* __restrict__ G)
{
    __shared__ uint16_t As[2][TM * BK];   // 2 x 16KB
    __shared__ uint16_t Bs[2][TN * BK];   // 2 x 20KB  (72KB total)
    const int tMb = blockIdx.x;           // 0..7
    const int tNb = blockIdx.y;           // 0..31
    const int t = threadIdx.x;
    const int wave = t >> 6;
    const int lane = t & 63;
    const int lane15 = lane & 15;
    const int quad = lane >> 4;
    const int m0 = (wave >> 1) * 64;      // 2x2 waves: each 64(M) x 80(N)
    const int n0 = (wave & 1) * 80;

    // staging: thread t -> row rA = t>>3 (32 rows/round), 16B chunk t&7.
    // LDS slot chunk (t&7) must hold logical chunk (t&7)^(rA&7) -> fetch that.
    const int rA = t >> 3;
    const int csrc = (t & 7) ^ (rA & 7);
    const uint16_t* Ag = E + (size_t)(tMb * TM + rA) * HID + csrc * 8;
    const uint16_t* Bg = W + (size_t)(tNb * TN + rA) * HID + csrc * 8;

    // ds_read physical chunk offsets (elems): logical chunk (kk*4|quad) ^ (row&7)
    const int l7 = lane15 & 7;
    const int pc0 = ((0 | quad) ^ l7) * 8;
    const int pc1 = ((4 | quad) ^ l7) * 8;

    f32x4 acc[4][5] = {};

#define STAGE(buf, k0) do {                                                    \
        _Pragma("unroll")                                                      \
        for (int r = 0; r < 4; ++r)                                            \
            GLD16(Ag + (k0) + (size_t)(r * 32) * HID, &As[buf][r * 2048 + t * 8]); \
        _Pragma("unroll")                                                      \
        for (int r = 0; r < 5; ++r)                                            \
            GLD16(Bg + (k0) + (size_t)(r * 32) * HID, &Bs[buf][r * 2048 + t * 8]); \
    } while (0)

    STAGE(0, 0);
    __syncthreads();               // prologue: buf0 ready

    int cur = 0;
    for (int kt = 0; kt < 16; ++kt) {
        if (kt < 15) STAGE(cur ^ 1, (kt + 1) * BK);   // prefetch next tile
        const uint16_t* Ac = As[cur];
        const uint16_t* Bc = Bs[cur];
        #pragma unroll
        for (int kk = 0; kk < 2; ++kk) {
            const int pc = kk ? pc1 : pc0;
            bf16x8 af[4], bv[5];
            #pragma unroll
            for (int im = 0; im < 4; ++im)
                af[im] = *(const bf16x8*)&Ac[(m0 + im * 16 + lane15) * BK + pc];
            #pragma unroll
            for (int in = 0; in < 5; ++in)
                bv[in] = *(const bf16x8*)&Bc[(n0 + in * 16 + lane15) * BK + pc];
            #pragma unroll
            for (int im = 0; im < 4; ++im)
                #pragma unroll
                for (int in = 0; in < 5; ++in)
                    acc[im][in] = __builtin_amdgcn_mfma_f32_16x16x32_bf16(
                        af[im], bv[in], acc[im][in], 0, 0, 0);
        }
        __syncthreads();           // drains prefetch vmcnt + protects reread
        cur ^= 1;
    }
#undef STAGE

    // epilogue: C/D layout col = lane&15 (n), row = quad*4 + reg (m)
    #pragma unroll
    for (int in = 0; in < 5; ++in) {
        const int n = tNb * TN + n0 + in * 16 + lane15;
        const int g = n >> 10;               // uniform per 16-wide subtile
        const int h = n & 1023;
        const float bias = brec[gate_off(g) + h];
        #pragma unroll
        for (int im = 0; im < 4; ++im) {
            const int mb = tMb * TM + m0 + im * 16 + quad * 4;
            #pragma unroll
            for (int r = 0; r < 4; ++r) {
                const float v = acc[im][in][r] + bias;
                float o;
                if (g == 1) {                       // gz: tanh
                    float e = __expf(2.f * v);
                    o = 1.f - 2.f / (e + 1.f);
                } else if (g == 4) {                // gd: softplus (stable)
                    o = fmaxf(v, 0.f) + log1pf(__expf(-fabsf(v)));
                } else {                            // gi/go/gib: sigmoid
                    o = 1.f / (1.f + __expf(-v));
                }
                G[((size_t)(mb + r) * 5 + g) * HID + h] = o;   // [type][gate][h]
            }
        }
    }
}

// ---------------------------------------------------------------------------
// Kernel 3: broadcast/expand. 2 events per block (MLP on the gather chain):
// all 10 G-row vector loads issued before any compute. G is [type][5][H]
// so one event's gates are a contiguous 20KB region.
// ---------------------------------------------------------------------------
__global__ __launch_bounds__(256) void expand_kernel(
    const int* __restrict__ ev, const float* __restrict__ dur,
    const float* __restrict__ G, float* __restrict__ out)
{
    const int tb0 = blockIdx.x * 2;
    const int tb1 = tb0 + 1;
    const int tid = threadIdx.x;

    int s0, s1;
    {
        const int t0 = tb0 >> 5, b0 = tb0 & 31;
        const int t1 = tb1 >> 5, b1 = tb1 & 31;
        s0 = b0 * SEQLEN + t0;              // inputs are [B, T]
        s1 = b1 * SEQLEN + t1;
    }
    const int   u0 = ev[s0],  u1 = ev[s1];
    const float d0 = dur[s0], d1 = dur[s1];

    const float* Ga = G + (size_t)u0 * (5 * HID);
    const float* Gb = G + (size_t)u1 * (5 * HID);

    f32x4 gi0  = *((const f32x4*)(Ga + 0 * HID) + tid);
    f32x4 gz0  = *((const f32x4*)(Ga + 1 * HID) + tid);
    f32x4 go0  = *((const f32x4*)(Ga + 2 * HID) + tid);
    f32x4 gib0 = *((const f32x4*)(Ga + 3 * HID) + tid);
    f32x4 gd0  = *((const f32x4*)(Ga + 4 * HID) + tid);
    f32x4 gi1  = *((const f32x4*)(Gb + 0 * HID) + tid);
    f32x4 gz1  = *((const f32x4*)(Gb + 1 * HID) + tid);
    f32x4 go1  = *((const f32x4*)(Gb + 2 * HID) + tid);
    f32x4 gib1 = *((const f32x4*)(Gb + 3 * HID) + tid);
    f32x4 gd1  = *((const f32x4*)(Gb + 4 * HID) + tid);

    f32x4 c0, cb0, hd0, c1, cb1, hd1;
    #pragma unroll
    for (int j = 0; j < 4; ++j) {
        float ci  = gi0[j] * gz0[j];
        float cbi = gib0[j] * gz0[j];
        float e   = __expf(-gd0[j] * d0);
        float cdi = cbi + (ci - cbi) * e;
        float t2  = __expf(2.f * cdi);
        c0[j] = ci; cb0[j] = cbi;
        hd0[j] = go0[j] * (1.f - 2.f / (t2 + 1.f));
    }
    #pragma unroll
    for (int j = 0; j < 4; ++j) {
        float ci  = gi1[j] * gz1[j];
        float cbi = gib1[j] * gz1[j];
        float e   = __expf(-gd1[j] * d1);
        float cdi = cbi + (ci - cbi) * e;
        float t2  = __expf(2.f * cdi);
        c1[j] = ci; cb1[j] = cbi;
        hd1[j] = go1[j] * (1.f - 2.f / (t2 + 1.f));
    }

    float* o0 = out + (size_t)tb0 * HID;
    float* o1 = out + (size_t)tb1 * HID;
    __builtin_nontemporal_store(hd0, (f32x4*)(o0 + 0 * TBH) + tid);
    __builtin_nontemporal_store(c0,  (f32x4*)(o0 + 1 * TBH) + tid);
    __builtin_nontemporal_store(cb0, (f32x4*)(o0 + 2 * TBH) + tid);
    __builtin_nontemporal_store(go0, (f32x4*)(o0 + 3 * TBH) + tid);
    __builtin_nontemporal_store(gd0, (f32x4*)(o0 + 4 * TBH) + tid);
    __builtin_nontemporal_store(hd1, (f32x4*)(o1 + 0 * TBH) + tid);
    __builtin_nontemporal_store(c1,  (f32x4*)(o1 + 1 * TBH) + tid);
    __builtin_nontemporal_store(cb1, (f32x4*)(o1 + 2 * TBH) + tid);
    __builtin_nontemporal_store(go1, (f32x4*)(o1 + 3 * TBH) + tid);
    __builtin_nontemporal_store(gd1, (f32x4*)(o1 + 4 * TBH) + tid);
}

// ---------------------------------------------------------------------------
extern "C" void kernel_launch(void* const* d_in, const int* in_sizes, int n_in,
                              void* d_out, int out_size, void* d_ws, size_t ws_size,
                              hipStream_t stream) {
    const int*   ev   = (const int*)d_in[0];
    const float* dur  = (const float*)d_in[1];
    const float* emb  = (const float*)d_in[2];
    const float* Wrec = (const float*)d_in[3];
    const float* brec = (const float*)d_in[4];
    float* out = (float*)d_out;

    // workspace layout:
    //   [0, 2MB)    Ebf  : bf16 [1024][1024]  (rows >=1001 garbage, never read)
    //   [2, 12MB)   Wbf  : bf16 [5120][1024]
    //   [12, 32MB)  G    : fp32 [1024][5][1024] activated gate table (interleaved)
    char* ws = (char*)d_ws;
    uint16_t* Ebf = (uint16_t*)ws;
    uint16_t* Wbf = (uint16_t*)(ws + (size_t)2 * 1024 * 1024);
    float*    G   = (float*)(ws + (size_t)12 * 1024 * 1024);

    convert_kernel<<<dim3(TYPES + NGATES), dim3(256), 0, stream>>>(emb, Wrec, Ebf, Wbf);
    gemm_gates<<<dim3(8, 32), dim3(256), 0, stream>>>(Ebf, Wbf, brec, G);
    expand_kernel<<<dim3(TB / 2), dim3(256), 0, stream>>>(ev, dur, G, out);
}

// Round 2
// 417.324 us; speedup vs baseline: 1.2511x; 1.2511x over previous
//
#include <hip/hip_runtime.h>
#include <stdint.h>

#define HID    1024
#define TYPES  1001
#define MPAD   1024
#define PLANE  ((size_t)MPAD * HID)      // floats per G4 plane (4MB)
#define NGATES 5120                      // 5 gates * 1024
#define BATCH  32
#define SEQLEN 512
#define TB     (BATCH * SEQLEN)          // 16384
#define TBH    ((size_t)TB * HID)        // floats per output plane

#define BK 64                            // K-step (bf16 -> 128B LDS rows)
#define TM 128                           // M tile (types)
#define TNH 32                           // h-columns per block; N-tile = 5 gates x 32 h

typedef __attribute__((ext_vector_type(4))) float  f32x4;
typedef __attribute__((ext_vector_type(8))) __bf16 bf16x8;

// round-to-nearest-even f32 -> bf16 bits
__device__ __forceinline__ uint32_t f2bf(float f) {
    uint32_t u = __float_as_uint(f);
    return (u + 0x7FFFu + ((u >> 16) & 1u)) >> 16;
}

// gate g in {0:gi,1:gz,2:go,3:gib,4:gd} -> source row offset in W_rec / b_rec
// offsets: gi=0, gz=2048, go=3072, gib=4096, gd=6144
__device__ __forceinline__ int gate_off(int g) {
    return (g + (g >= 1) + (g >= 4)) << 10;
}

// async global->LDS, 16B per lane (LDS dest must be uniform-base + lane*16)
#define GLD16(gp, lp) __builtin_amdgcn_global_load_lds(                        \
    (const __attribute__((address_space(1))) void*)(uintptr_t)(gp),            \
    (__attribute__((address_space(3))) void*)(uint32_t)(uintptr_t)(lp),        \
    16, 0, 0)

// ---------------------------------------------------------------------------
// Kernel 1: convert emb (1001x1024) and gathered W rows (5120x1024) to bf16.
// ---------------------------------------------------------------------------
__global__ __launch_bounds__(256) void convert_kernel(
    const float* __restrict__ emb, const float* __restrict__ Wrec,
    uint16_t* __restrict__ Ebf, uint16_t* __restrict__ Wbf)
{
    const int row = blockIdx.x;
    const int tid = threadIdx.x;
    const float* src;
    uint16_t* dst;
    if (row < TYPES) {
        src = emb + (size_t)row * HID;
        dst = Ebf + (size_t)row * HID;
    } else {
        const int n = row - TYPES;           // 0..5119
        const int g = n >> 10;
        const int h = n & 1023;
        src = Wrec + (size_t)(gate_off(g) + h) * (2 * HID);  // W_rec row stride = 2H
        dst = Wbf + (size_t)n * HID;
    }
    float4 v = ((const float4*)src)[tid];
    uint2 p;
    p.x = f2bf(v.x) | (f2bf(v.y) << 16);
    p.y = f2bf(v.z) | (f2bf(v.w) << 16);
    ((uint2*)dst)[tid] = p;
}

// ---------------------------------------------------------------------------
// Kernel 2: bf16 MFMA GEMM with fused gate combine.
// Tile: 128(M types) x [5 gates x 32 h](N), BK=64, double-buffered LDS,
// prefetch-before-compute. grid = (8,32) = 256 blocks = 1/CU.
// Wave layout: 2x2 waves, each wave = 64 M x (5 gates x 16 h).
// Since each wave holds ALL 5 gate raw values for the same (m,h), the
// epilogue computes c = sig(gi)*tanh(gz), cb = sig(gib)*tanh(gz) directly
// and stores 4 planar planes G4[p][m][h], p in {c, cb, go, gd}.
// LDS rows are 128B -> XOR-swizzle 16B chunks (chunk ^= row&7); since
// global_load_lds writes linearly, the *global source* chunk is pre-swizzled
// and the ds_read applies the same XOR (both-sides rule).
// ---------------------------------------------------------------------------
__global__ __launch_bounds__(256) void gemm_gates(
    const uint16_t* __restrict__ E, const uint16_t* __restrict__ W,
    const float* __restrict__ brec, float* __restrict__ G4)
{
    __shared__ uint16_t As[2][TM * BK];    // 2 x 16KB
    __shared__ uint16_t Bs[2][160 * BK];   // 2 x 20KB  (72KB total)
    const int tMb = blockIdx.x;           // 0..7
    const int tNb = blockIdx.y;           // 0..31
    const int t = threadIdx.x;
    const int wave = t >> 6;
    const int lane = t & 63;
    const int lane15 = lane & 15;
    const int quad = lane >> 4;
    const int m0 = (wave >> 1) * 64;      // 2x2 waves
    const int n0h = (wave & 1) * 16;      // h-offset within block's 32 h

    // staging: thread t -> LDS row rA = t>>3 (32 rows/round), 16B chunk t&7.
    // LDS slot chunk (t&7) must hold logical chunk (t&7)^(rA&7) -> fetch that.
    const int rA = t >> 3;
    const int csrc = (t & 7) ^ (rA & 7);
    const uint16_t* Ag = E + (size_t)(tMb * TM + rA) * HID + csrc * 8;
    // B LDS row nloc = g*32 + hh  <->  Wbf row g*1024 + tNb*32 + hh
    const uint16_t* Bg = W + (size_t)(tNb * TNH + rA) * HID + csrc * 8;

    // ds_read physical chunk offsets (elems): logical chunk (kk*4|quad) ^ (row&7)
    const int l7 = lane15 & 7;
    const int pc0 = ((0 | quad) ^ l7) * 8;
    const int pc1 = ((4 | quad) ^ l7) * 8;

    f32x4 acc[4][5] = {};

#define STAGE(buf, k0) do {                                                      \
        _Pragma("unroll")                                                        \
        for (int r = 0; r < 4; ++r)                                              \
            GLD16(Ag + (k0) + (size_t)(r * 32) * HID, &As[buf][r * 2048 + t * 8]); \
        _Pragma("unroll")                                                        \
        for (int r = 0; r < 5; ++r)                                              \
            GLD16(Bg + (k0) + (size_t)(r * 1024) * HID, &Bs[buf][r * 2048 + t * 8]); \
    } while (0)

    STAGE(0, 0);
    __syncthreads();               // prologue: buf0 ready

    int cur = 0;
    for (int kt = 0; kt < 16; ++kt) {
        if (kt < 15) STAGE(cur ^ 1, (kt + 1) * BK);   // prefetch next tile
        const uint16_t* Ac = As[cur];
        const uint16_t* Bc = Bs[cur];
        #pragma unroll
        for (int kk = 0; kk < 2; ++kk) {
            const int pc = kk ? pc1 : pc0;
            bf16x8 af[4], bv[5];
            #pragma unroll
            for (int im = 0; im < 4; ++im)
                af[im] = *(const bf16x8*)&Ac[(m0 + im * 16 + lane15) * BK + pc];
            #pragma unroll
            for (int in = 0; in < 5; ++in)      // in = gate index
                bv[in] = *(const bf16x8*)&Bc[(in * 32 + n0h + lane15) * BK + pc];
            #pragma unroll
            for (int im = 0; im < 4; ++im)
                #pragma unroll
                for (int in = 0; in < 5; ++in)
                    acc[im][in] = __builtin_amdgcn_mfma_f32_16x16x32_bf16(
                        af[im], bv[in], acc[im][in], 0, 0, 0);
        }
        __syncthreads();           // drains prefetch vmcnt + protects reread
        cur ^= 1;
    }
#undef STAGE

    // epilogue: C/D layout col = lane&15 (n=h), row = quad*4 + reg (m).
    // Lane holds all 5 gate raw values for the same (m, h) -> fuse here.
    const int h = tNb * TNH + n0h + lane15;
    const float b0 = brec[0    + h];
    const float b1 = brec[2048 + h];
    const float b2 = brec[3072 + h];
    const float b3 = brec[4096 + h];
    const float b4 = brec[6144 + h];
    #pragma unroll
    for (int im = 0; im < 4; ++im) {
        const int mb = tMb * TM + m0 + im * 16 + quad * 4;
        #pragma unroll
        for (int r = 0; r < 4; ++r) {
            const float vi  = acc[im][0][r] + b0;
            const float vz  = acc[im][1][r] + b1;
            const float vo  = acc[im][2][r] + b2;
            const float vib = acc[im][3][r] + b3;
            const float vd  = acc[im][4][r] + b4;
            const float gi  = 1.f / (1.f + __expf(-vi));
            const float ez  = __expf(2.f * vz);
            const float gz  = 1.f - 2.f / (ez + 1.f);          // tanh
            const float go  = 1.f / (1.f + __expf(-vo));
            const float gib = 1.f / (1.f + __expf(-vib));
            const float gd  = fmaxf(vd, 0.f) + log1pf(__expf(-fabsf(vd)));  // softplus
            const size_t base = (size_t)(mb + r) * HID + h;
            G4[0 * PLANE + base] = gi * gz;    // c
            G4[1 * PLANE + base] = gib * gz;   // c_bar
            G4[2 * PLANE + base] = go;
            G4[3 * PLANE + base] = gd;
        }
    }
}

// ---------------------------------------------------------------------------
// Kernel 3: broadcast/expand. One block per (t,b): gather the 4 table rows
// for type u, compute duration-dependent h_d, write all 5 output planes.
// out[s, t, b, h] ; s in {h_d, c, c_bar, go, gd}
// ---------------------------------------------------------------------------
__global__ __launch_bounds__(256) void expand_kernel(
    const int* __restrict__ ev, const float* __restrict__ dur,
    const float* __restrict__ G4, float* __restrict__ out)
{
    const int tb = blockIdx.x;       // = t*32 + b
    const int t = tb >> 5;
    const int b = tb & 31;
    const int src = b * SEQLEN + t;  // inputs are [B, T]
    const int u = ev[src];
    const float d = dur[src];
    const int tid = threadIdx.x;

    const float* Gu = G4 + (size_t)u * HID;
    f32x4 c  = *((const f32x4*)(Gu + 0 * PLANE) + tid);
    f32x4 cb = *((const f32x4*)(Gu + 1 * PLANE) + tid);
    f32x4 go = *((const f32x4*)(Gu + 2 * PLANE) + tid);
    f32x4 gd = *((const f32x4*)(Gu + 3 * PLANE) + tid);

    f32x4 hd;
    #pragma unroll
    for (int j = 0; j < 4; j++) {
        float e   = __expf(-gd[j] * d);
        float cdi = cb[j] + (c[j] - cb[j]) * e;   // |cdi| <= 1, tanh safe
        float t2  = __expf(2.f * cdi);
        hd[j] = go[j] * (1.f - 2.f / (t2 + 1.f));
    }

    float* o = out + (size_t)tb * HID;
    __builtin_nontemporal_store(hd, (f32x4*)(o + 0 * TBH) + tid);
    __builtin_nontemporal_store(c,  (f32x4*)(o + 1 * TBH) + tid);
    __builtin_nontemporal_store(cb, (f32x4*)(o + 2 * TBH) + tid);
    __builtin_nontemporal_store(go, (f32x4*)(o + 3 * TBH) + tid);
    __builtin_nontemporal_store(gd, (f32x4*)(o + 4 * TBH) + tid);
}

// ---------------------------------------------------------------------------
extern "C" void kernel_launch(void* const* d_in, const int* in_sizes, int n_in,
                              void* d_out, int out_size, void* d_ws, size_t ws_size,
                              hipStream_t stream) {
    const int*   ev   = (const int*)d_in[0];
    const float* dur  = (const float*)d_in[1];
    const float* emb  = (const float*)d_in[2];
    const float* Wrec = (const float*)d_in[3];
    const float* brec = (const float*)d_in[4];
    float* out = (float*)d_out;

    // workspace layout:
    //   [0, 2MB)    Ebf  : bf16 [1024][1024]  (rows >=1001 garbage, never read)
    //   [2, 12MB)   Wbf  : bf16 [5120][1024]
    //   [12, 28MB)  G4   : fp32 [4][1024][1024] planar: {c, c_bar, go, gd}
    char* ws = (char*)d_ws;
    uint16_t* Ebf = (uint16_t*)ws;
    uint16_t* Wbf = (uint16_t*)(ws + (size_t)2 * 1024 * 1024);
    float*    G4  = (float*)(ws + (size_t)12 * 1024 * 1024);

    convert_kernel<<<dim3(TYPES + NGATES), dim3(256), 0, stream>>>(emb, Wrec, Ebf, Wbf);
    gemm_gates<<<dim3(8, 32), dim3(256), 0, stream>>>(Ebf, Wbf, brec, G4);
    expand_kernel<<<dim3(TB), dim3(256), 0, stream>>>(ev, dur, G4, out);
}